// Round 2
// baseline (1785.734 us; speedup 1.0000x reference)
//
#include <hip/hip_runtime.h>

// APPNP: h0 = relu(x@W1+b1)@W2+b2 ; 10x: h = 0.9*(D^-1/2 A_sl D^-1/2 h) + 0.1*h0
// R2 build: bucket-binned CSR (64 dst/bucket), LDS per-bucket build.
// R3 mlp: W1/W2 pre-packed in MFMA frag order (global->VGPR B), h1s XOR-swizzled.
// R4 (this round):
//   - prop sliced: hs stored as 4 column-slices [s][N][16] fp16 (3.2 MB each ->
//     fits 4MB per-XCD L2). gridDim.y = slice; chip walks one L2-resident slice
//     at a time. 8 lanes/node, 4B gathers (2 cols/lane). csr re-read x4 (LLC).
//   - mlp GEMM1: A-frags loaded DIRECTLY from global in fragment layout
//     (2x16B/lane/row, f2bf in reg). No LDS staging, no barriers in GEMM1.
//     Single __syncthreads before GEMM2 (h1s handoff).

typedef unsigned short u16;
typedef unsigned int   u32;
typedef __bf16    bfx8  __attribute__((ext_vector_type(8)));
typedef _Float16  h16x8 __attribute__((ext_vector_type(8)));
typedef _Float16  h16x2 __attribute__((ext_vector_type(2)));
typedef float     f32x4 __attribute__((ext_vector_type(4)));

#define CAP 4096      // per-bucket edge capacity (mean 2048, sigma 45)
#define EPB 16384     // edges per binscat block
#define NBMAX 1792    // bucket count upper bound for LDS arrays (N<=114k)

__device__ __forceinline__ u16 f2bf(float f) {
    u32 u = __float_as_uint(f);
    u += 0x7fffu + ((u >> 16) & 1u);   // RNE
    return (u16)(u >> 16);
}

__device__ __forceinline__ bfx8 pack_bf8(float4 a, float4 b) {
    union { u32 u[4]; bfx8 v; } c;
    c.u[0] = (u32)f2bf(a.x) | ((u32)f2bf(a.y) << 16);
    c.u[1] = (u32)f2bf(a.z) | ((u32)f2bf(a.w) << 16);
    c.u[2] = (u32)f2bf(b.x) | ((u32)f2bf(b.y) << 16);
    c.u[3] = (u32)f2bf(b.z) | ((u32)f2bf(b.w) << 16);
    return c.v;
}

// ---------------- build pass 1: bin edges by dst bucket ----------------

__global__ __launch_bounds__(256) void binscat_kernel(
        const int* __restrict__ src, const int* __restrict__ dst,
        int* __restrict__ gcur, u32* __restrict__ binned, int E, int NB) {
    __shared__ int cnt[NBMAX];
    int tid = threadIdx.x;
#pragma unroll
    for (int j = 0; j < NBMAX / 256; ++j) cnt[tid + j * 256] = 0;
    __syncthreads();
    int e0 = blockIdx.x * EPB;
    for (int r = 0; r < EPB / 256; ++r) {
        int i = e0 + r * 256 + tid;
        if (i < E) atomicAdd(&cnt[dst[i] >> 6], 1);
    }
    __syncthreads();
    for (int j = 0; j < NBMAX / 256; ++j) {
        int b = tid + j * 256;
        if (b < NB) {
            int c = cnt[b];
            cnt[b] = (c > 0) ? atomicAdd(&gcur[b], c) : 0;
        }
    }
    __syncthreads();
    for (int r = 0; r < EPB / 256; ++r) {
        int i = e0 + r * 256 + tid;
        if (i < E) {
            int d = dst[i];
            int s = src[i];
            int bb = d >> 6;
            int p = atomicAdd(&cnt[bb], 1);
            if (p < CAP) binned[(size_t)bb * CAP + p] = ((u32)(d & 63) << 17) | (u32)s;
        }
    }
}

// ---------------- build pass 2: exclusive scan of bucket counts ----------------

__global__ __launch_bounds__(256) void bucket_scan_kernel(
        const int* __restrict__ gcur, int* __restrict__ bbase,
        int* __restrict__ rp, int N, int NB) {
    __shared__ int tsum[256];
    int tid = threadIdx.x;
    int loc[7];
    int run = 0;
#pragma unroll
    for (int j = 0; j < 7; ++j) {
        int b = tid * 7 + j;
        int v = 0;
        if (b < NB) { v = gcur[b]; if (v > CAP) v = CAP; }
        loc[j] = run;
        run += v;
    }
    tsum[tid] = run;
    __syncthreads();
    for (int off = 1; off < 256; off <<= 1) {
        int t = (tid >= off) ? tsum[tid - off] : 0;
        __syncthreads();
        tsum[tid] += t;
        __syncthreads();
    }
    int texcl = tsum[tid] - run;
#pragma unroll
    for (int j = 0; j < 7; ++j) {
        int b = tid * 7 + j;
        if (b < NB) bbase[b] = texcl + loc[j];
    }
    if (tid == 255) rp[N] = tsum[255];   // == E
}

// ---------------- build pass 3: per-bucket CSR in LDS (+rp,+dinv) ----------------

__global__ __launch_bounds__(256) void buildcsr_kernel(
        const u32* __restrict__ binned, const int* __restrict__ gcur,
        const int* __restrict__ bbase, int* __restrict__ rp,
        float* __restrict__ dinv, int* __restrict__ csr, int N) {
    __shared__ u32 eb[CAP];
    __shared__ int lcsr[CAP];
    __shared__ int ncnt[64];
    __shared__ int lcur[64];
    int b = blockIdx.x;
    int tid = threadIdx.x;
    int cnt = gcur[b]; if (cnt > CAP) cnt = CAP;
    int base = bbase[b];
    if (tid < 64) ncnt[tid] = 0;
    __syncthreads();
    for (int idx = tid; idx < cnt; idx += 256) {
        u32 v = binned[(size_t)b * CAP + idx];
        eb[idx] = v;
        atomicAdd(&ncnt[v >> 17], 1);
    }
    __syncthreads();
    if (tid < 64) {
        int c = ncnt[tid];
        int s = c;
#pragma unroll
        for (int off = 1; off < 64; off <<= 1) {
            int t = __shfl_up(s, off);
            if (tid >= off) s += t;
        }
        int excl = s - c;
        lcur[tid] = excl;
        int node = b * 64 + tid;
        if (node < N) {
            rp[node] = base + excl;
            dinv[node] = rsqrtf(1.0f + (float)c);
        }
    }
    __syncthreads();
    for (int idx = tid; idx < cnt; idx += 256) {
        u32 v = eb[idx];
        int p = atomicAdd(&lcur[v >> 17], 1);
        lcsr[p] = (int)(v & 0x1FFFFu);
    }
    __syncthreads();
    for (int idx = tid; idx < cnt; idx += 256)
        csr[base + idx] = lcsr[idx];
}

// ---------------- weight pre-pack to MFMA fragment order (bf16) ----------------

__global__ void prepw1_kernel(const float* __restrict__ W1, u16* __restrict__ W1f) {
    int f = blockIdx.x * 256 + threadIdx.x;   // 16384 frags
    int lane = f & 63;
    int nt = (f >> 6) & 3;
    int w  = (f >> 8) & 3;
    int t  = f >> 10;
    int col = w * 64 + nt * 16 + (lane & 15);
    int k0  = t * 32 + ((lane >> 4) << 3);
    u32 pk[4];
#pragma unroll
    for (int j = 0; j < 4; ++j) {
        u16 lo = f2bf(W1[(size_t)(k0 + 2 * j) * 256 + col]);
        u16 hi = f2bf(W1[(size_t)(k0 + 2 * j + 1) * 256 + col]);
        pk[j] = (u32)lo | ((u32)hi << 16);
    }
    *(uint4*)&W1f[(size_t)f * 8] = make_uint4(pk[0], pk[1], pk[2], pk[3]);
}

__global__ void prepw2_kernel(const float* __restrict__ W2, u16* __restrict__ W2f) {
    int f = blockIdx.x * 256 + threadIdx.x;   // 2048 frags
    int lane = f & 63;
    int nt = (f >> 6) & 3;
    int t  = f >> 8;
    int col = nt * 16 + (lane & 15);
    int k0  = t * 32 + ((lane >> 4) << 3);
    u32 pk[4];
#pragma unroll
    for (int j = 0; j < 4; ++j) {
        u16 lo = f2bf(W2[(size_t)(k0 + 2 * j) * 64 + col]);
        u16 hi = f2bf(W2[(size_t)(k0 + 2 * j + 1) * 64 + col]);
        pk[j] = (u32)lo | ((u32)hi << 16);
    }
    *(uint4*)&W2f[(size_t)f * 8] = make_uint4(pk[0], pk[1], pk[2], pk[3]);
}

// ---------------- fused MLP -> h0 (fp32, dense) and hs = dinv*h0 (fp16, SLICED) ----------------
// block: 64 rows, 4 waves. GEMM1: A-frags straight from global in frag layout
// (rows mt*16+lr, k = t*32+lq*8..+8 -> 2x float4/lane), B-frags from W1f. No LDS,
// no barriers. GEMM2 via swizzled h1s as before.

__global__ __launch_bounds__(256) void mlp_kernel(
        const float* __restrict__ x, const u16* __restrict__ W1f,
        const float* __restrict__ b1, const u16* __restrict__ W2f,
        const float* __restrict__ b2, const float* __restrict__ dinv,
        float* __restrict__ h0, _Float16* __restrict__ hA, int N) {
    __shared__ u16 h1s[64 * 256];      // 32 KB, swizzled

    const int tid  = threadIdx.x;
    const int wave = tid >> 6;
    const int lane = tid & 63;
    const int lq   = lane >> 4;
    const int lr   = lane & 15;
    const int blockRow = blockIdx.x * 64;

    // A row pointers for the 4 mt sub-tiles (frag layout: row = mt*16+lr, k-chunk = lq*8)
    const float* xr[4];
    bool vr[4];
#pragma unroll
    for (int mt = 0; mt < 4; ++mt) {
        int r = blockRow + mt * 16 + lr;
        vr[mt] = (r < N);
        xr[mt] = x + (size_t)(vr[mt] ? r : 0) * 512 + lq * 8;
    }

    f32x4 acc[4][4];
#pragma unroll
    for (int a = 0; a < 4; ++a)
#pragma unroll
        for (int b = 0; b < 4; ++b) acc[a][b] = (f32x4){0.f, 0.f, 0.f, 0.f};

    const bfx8* w1q = (const bfx8*)W1f;
    const float4 z4 = make_float4(0.f, 0.f, 0.f, 0.f);

    // ---- GEMM1: K=512 in 16 steps of 32, barrier-free ----
#pragma unroll 2
    for (int t = 0; t < 16; ++t) {
        bfx8 fb[4];
#pragma unroll
        for (int n = 0; n < 4; ++n)
            fb[n] = w1q[(t * 16 + wave * 4 + n) * 64 + lane];
        bfx8 fa[4];
#pragma unroll
        for (int mt = 0; mt < 4; ++mt) {
            float4 u0 = vr[mt] ? *(const float4*)(xr[mt] + t * 32)     : z4;
            float4 u1 = vr[mt] ? *(const float4*)(xr[mt] + t * 32 + 4) : z4;
            fa[mt] = pack_bf8(u0, u1);
        }
#pragma unroll
        for (int mt = 0; mt < 4; ++mt) {
            acc[mt][0] = __builtin_amdgcn_mfma_f32_16x16x32_bf16(fa[mt], fb[0], acc[mt][0], 0, 0, 0);
            acc[mt][1] = __builtin_amdgcn_mfma_f32_16x16x32_bf16(fa[mt], fb[1], acc[mt][1], 0, 0, 0);
            acc[mt][2] = __builtin_amdgcn_mfma_f32_16x16x32_bf16(fa[mt], fb[2], acc[mt][2], 0, 0, 0);
            acc[mt][3] = __builtin_amdgcn_mfma_f32_16x16x32_bf16(fa[mt], fb[3], acc[mt][3], 0, 0, 0);
        }
    }

    // ---- epilogue1: bias+relu -> h1s (bf16, swizzled col ^= (row&7)<<3) ----
#pragma unroll
    for (int nt = 0; nt < 4; ++nt) {
        int col = wave * 64 + nt * 16 + lr;
        float bb = b1[col];
#pragma unroll
        for (int mt = 0; mt < 4; ++mt)
#pragma unroll
            for (int r = 0; r < 4; ++r) {
                int row = mt * 16 + lq * 4 + r;
                float vv = acc[mt][nt][r] + bb;
                vv = vv > 0.f ? vv : 0.f;
                h1s[row * 256 + (col ^ ((row & 7) << 3))] = f2bf(vv);
            }
    }
    __syncthreads();

    // ---- GEMM2: wave w -> rows [16w,16w+16), cols 0..63, K=256 ----
    f32x4 acc2[4];
#pragma unroll
    for (int a = 0; a < 4; ++a) acc2[a] = (f32x4){0.f, 0.f, 0.f, 0.f};
    const bfx8* w2q = (const bfx8*)W2f;
    const int row2 = wave * 16 + lr;
    const int sw2  = (row2 & 7) << 3;
#pragma unroll
    for (int t2 = 0; t2 < 8; ++t2) {
        bfx8 a = *(const bfx8*)&h1s[row2 * 256 + ((t2 * 32 + lq * 8) ^ sw2)];
#pragma unroll
        for (int nt = 0; nt < 4; ++nt) {
            bfx8 b = w2q[(t2 * 4 + nt) * 64 + lane];
            acc2[nt] = __builtin_amdgcn_mfma_f32_16x16x32_bf16(a, b, acc2[nt], 0, 0, 0);
        }
    }

    // ---- epilogue2: bias; h0 dense fp32; hA sliced fp16 (slice = nt, col-in-slice = lr) ----
#pragma unroll
    for (int nt = 0; nt < 4; ++nt) {
        int col = nt * 16 + lr;
        float bb = b2[col];
#pragma unroll
        for (int r = 0; r < 4; ++r) {
            int row = wave * 16 + lq * 4 + r;
            int g = blockRow + row;
            if (g < N) {
                float vv = acc2[nt][r] + bb;
                h0[(size_t)g * 64 + col] = vv;
                hA[(size_t)nt * N * 16 + (size_t)g * 16 + lr] = (_Float16)(vv * dinv[g]);
            }
        }
    }
}

// ---------------- propagation: column-sliced, 8 lanes/node, 2 cols (4B)/lane ----------------
// hs layout: [slice][N][16] fp16 (3.2 MB/slice -> per-XCD-L2 resident).
// blockIdx.y = slice; blocks within a slice walk nodes. Gathers hit L2.

template <typename OUTT>
__global__ __launch_bounds__(256) void prop_kernel(
        const _Float16* __restrict__ hs, const float* __restrict__ h0,
        const float* __restrict__ dinv, const int* __restrict__ rp,
        const int* __restrict__ csr, OUTT* __restrict__ hout, int N) {
    const int s = blockIdx.y;                       // slice 0..3
    int t = blockIdx.x * 256 + threadIdx.x;
    int i = t >> 3;                                 // node
    int l = t & 7;                                  // 2-col lane
    if (i >= N) return;
    int beg = rp[i], end = rp[i + 1];
    const _Float16* hb = hs + (size_t)s * N * 16 + l * 2;
    h16x2 self = *(const h16x2*)(hb + (size_t)i * 16);
    float a0 = (float)self[0];
    float a1 = (float)self[1];                      // self-loop folded into init
    int e = beg;
    for (; e + 3 < end; e += 4) {
        int s0 = csr[e], s1 = csr[e + 1], s2 = csr[e + 2], s3 = csr[e + 3];
        h16x2 g0 = *(const h16x2*)(hb + (size_t)s0 * 16);
        h16x2 g1 = *(const h16x2*)(hb + (size_t)s1 * 16);
        h16x2 g2 = *(const h16x2*)(hb + (size_t)s2 * 16);
        h16x2 g3 = *(const h16x2*)(hb + (size_t)s3 * 16);
        a0 += (float)g0[0]; a1 += (float)g0[1];
        a0 += (float)g1[0]; a1 += (float)g1[1];
        a0 += (float)g2[0]; a1 += (float)g2[1];
        a0 += (float)g3[0]; a1 += (float)g3[1];
    }
    for (; e < end; ++e) {
        int s0 = csr[e];
        h16x2 g0 = *(const h16x2*)(hb + (size_t)s0 * 16);
        a0 += (float)g0[0]; a1 += (float)g0[1];
    }
    float dv = dinv[i];
    float c1 = 0.9f * dv;
    const float* h0p = h0 + (size_t)i * 64 + s * 16 + l * 2;
    float o0 = fmaf(c1, a0, 0.1f * h0p[0]);
    float o1 = fmaf(c1, a1, 0.1f * h0p[1]);
    if constexpr (sizeof(OUTT) == 2) {
        h16x2 ov;
        ov[0] = (_Float16)(dv * o0);
        ov[1] = (_Float16)(dv * o1);                // store hs_new (sliced)
        *(h16x2*)((_Float16*)hout + (size_t)s * N * 16 + (size_t)i * 16 + l * 2) = ov;
    } else {
        *(float2*)((float*)hout + (size_t)i * 64 + s * 16 + l * 2) = make_float2(o0, o1);
    }
}

// ---------------- launch ----------------

extern "C" void kernel_launch(void* const* d_in, const int* in_sizes, int n_in,
                              void* d_out, int out_size, void* d_ws, size_t ws_size,
                              hipStream_t stream) {
    const float* x  = (const float*)d_in[0];
    const int*   ei = (const int*)d_in[1];
    const float* W1 = (const float*)d_in[2];
    const float* b1 = (const float*)d_in[3];
    const float* W2 = (const float*)d_in[4];
    const float* b2 = (const float*)d_in[5];
    const int N = in_sizes[0] / 512;
    const int E = in_sizes[1] / 2;
    const int NB = (N + 63) / 64;
    const int* src = ei;
    const int* dst = ei + E;

    char* w = (char*)d_ws;
    size_t off = 0;
    auto alloc = [&](size_t bytes) -> char* {
        char* p = w + off;
        off = (off + bytes + 1023) & ~(size_t)1023;
        return p;
    };
    int*      gcur  = (int*)alloc((size_t)NB * 4);
    int*      bbase = (int*)alloc((size_t)NB * 4);
    int*      rp    = (int*)alloc(((size_t)N + 1) * 4);
    float*    dinv  = (float*)alloc((size_t)N * 4);
    int*      csr   = (int*)alloc((size_t)E * 4);
    u32*      binned= (u32*)alloc((size_t)NB * CAP * 4);
    u16*      W1f   = (u16*)alloc(512 * 256 * 2);
    u16*      W2f   = (u16*)alloc(256 * 64 * 2);
    float*    h0    = (float*)alloc((size_t)N * 64 * 4);
    _Float16* hA    = (_Float16*)alloc((size_t)N * 64 * 2);
    _Float16* hB    = (_Float16*)alloc((size_t)N * 64 * 2);
    // ws use ~91 MB

    hipMemsetAsync(gcur, 0, (size_t)NB * 4, stream);
    binscat_kernel<<<(E + EPB - 1) / EPB, 256, 0, stream>>>(src, dst, gcur, binned, E, NB);
    bucket_scan_kernel<<<1, 256, 0, stream>>>(gcur, bbase, rp, N, NB);
    buildcsr_kernel<<<NB, 256, 0, stream>>>(binned, gcur, bbase, rp, dinv, csr, N);
    prepw1_kernel<<<64, 256, 0, stream>>>(W1, W1f);
    prepw2_kernel<<<8, 256, 0, stream>>>(W2, W2f);
    mlp_kernel<<<(N + 63) / 64, 256, 0, stream>>>(x, W1f, b1, W2f, b2, dinv, h0, hA, N);

    const _Float16* pin = hA;
    dim3 pgrid((N * 8 + 255) / 256, 4);
    for (int it = 0; it < 9; ++it) {
        _Float16* pout = (it & 1) ? hA : hB;
        prop_kernel<_Float16><<<pgrid, 256, 0, stream>>>(pin, h0, dinv, rp, csr, pout, N);
        pin = pout;
    }
    prop_kernel<float><<<pgrid, 256, 0, stream>>>(pin, h0, dinv, rp, csr, (float*)d_out, N);
}